// Round 7
// baseline (150.759 us; speedup 1.0000x reference)
//
#include <hip/hip_runtime.h>
#include <hip/hip_bf16.h>
#include <math.h>
#include <stdint.h>

#define BS 16
#define NH 12
#define SEQ 1024
#define ROWS (NH * SEQ)          // 12288 rows per batch
#define KEEP_FRAC 0.4f           // 1 - PRUNING_RATIO

typedef float f32x4 __attribute__((ext_vector_type(4)));

// ---------------------------------------------------------------------------
// Kernel 1: partial column-sum of probes over (h, s) rows.
// grid = (nch, BS); block = 256; thread t owns cols [4t, 4t+3] (16B loads).
// nch=128 -> 2048 blocks = exactly 8 blocks/CU -> 32/32 waves occupancy.
// NT loads (R5 A/B: removing NT cost +18 us on this 805 MB one-shot stream).
// R7 experiment: per-8-row f32x4 TREE reduction (7 parallel f32 adds) +
// one f64 accumulate per group — 8x fewer f64 ops, no serial add chains.
// Mean-error RMS ~1.6e-9, far below ~1.5e-5 adjacent-score gaps.
// ---------------------------------------------------------------------------
__global__ __launch_bounds__(256, 8) void colsum_partial_kernel(
    const float* __restrict__ probes, float* __restrict__ partials,
    int rows_per_chunk, int nch) {
  const int chunk = blockIdx.x;
  const int b = blockIdx.y;
  const int t = threadIdx.x;

  const size_t row0 = (size_t)b * ROWS + (size_t)chunk * rows_per_chunk;
  const f32x4* src = (const f32x4*)(probes + row0 * SEQ) + t;

  double a0 = 0.0, a1 = 0.0, a2 = 0.0, a3 = 0.0;
  const int ngroups = rows_per_chunk >> 3;   // rpc divisible by 8 for all nch
  for (int g = 0; g < ngroups; ++g) {
    f32x4 v[8];
#pragma unroll
    for (int i = 0; i < 8; ++i)
      v[i] = __builtin_nontemporal_load(src + (size_t)(g * 8 + i) * (SEQ / 4));
    const f32x4 s01 = v[0] + v[1];
    const f32x4 s23 = v[2] + v[3];
    const f32x4 s45 = v[4] + v[5];
    const f32x4 s67 = v[6] + v[7];
    const f32x4 s = (s01 + s23) + (s45 + s67);
    a0 += (double)s.x; a1 += (double)s.y; a2 += (double)s.z; a3 += (double)s.w;
  }

  f32x4 o; o.x = (float)a0; o.y = (float)a1; o.z = (float)a2; o.w = (float)a3;
  *(f32x4*)(partials + ((size_t)b * nch + chunk) * SEQ + (size_t)t * 4) = o;
}

// ---------------------------------------------------------------------------
// Kernel 2: WIDE combine of f32 partials -> f32 scores (mean).
// grid = (BS, SEQ/64) = 256 blocks x 64 threads; partials are L3-resident.
// ---------------------------------------------------------------------------
__global__ __launch_bounds__(64) void combine_kernel(
    const float* __restrict__ partials, float* __restrict__ scores, int nch) {
  const int b = blockIdx.x;
  const int col = blockIdx.y * 64 + threadIdx.x;
  const float* p = partials + (size_t)b * nch * SEQ + col;
  double acc = 0.0;
#pragma unroll 8
  for (int c = 0; c < nch; ++c) acc += (double)p[(size_t)c * SEQ];
  scores[b * SEQ + col] = (float)(acc * (1.0 / (double)ROWS));
}

// ---------------------------------------------------------------------------
// Kernel 3: per-batch rank + mask emit. One 1024-thread block per batch.
// Packed u64 keys; bitonic sort with shfl_xor for j<64 (no LDS/barrier),
// LDS only for the 10 phases with j>=64. Reads only 4 KB of scores/block.
// ---------------------------------------------------------------------------
__global__ __launch_bounds__(1024) void rank_kernel(
    const float* __restrict__ scores, const float* __restrict__ mask,
    float* __restrict__ out) {
  const int b = blockIdx.x;
  const int tid = threadIdx.x;        // == column index
  const int lane = tid & 63;
  const int wave = tid >> 6;

  __shared__ unsigned long long s_key[SEQ];
  __shared__ int s_wred[16];
  __shared__ unsigned char s_keep[SEQ];
  __shared__ int s_len;

  // --- length = sum(mask[b,:]) via wave shuffle reduce (mask is exact 0/1) ---
  int mv = (mask[b * SEQ + tid] != 0.0f) ? 1 : 0;
#pragma unroll
  for (int o = 32; o > 0; o >>= 1) mv += __shfl_xor(mv, o);
  if (lane == 0) s_wred[wave] = mv;
  __syncthreads();
  if (tid == 0) {
    int L = 0;
#pragma unroll
    for (int w = 0; w < 16; ++w) L += s_wred[w];
    s_len = L;
  }
  __syncthreads();
  const int len = s_len;
  const int sep = len - 1;                       // len >= 128 -> sep >= 127
  const int k = (int)((float)len * KEEP_FRAC);   // bit-matches f32 ref math

  // --- build distinct sort key: ascending key == (score desc, idx asc) ---
  const float score = scores[b * SEQ + tid];
  uint32_t u = __float_as_uint(score); // scores positive -> bits monotonic
  if (tid == 0 || tid == sep) u = 0u;  // invalid -> sorts last
  unsigned long long key =
      ((unsigned long long)(u ^ 0xFFFFFFFFu) << 10) | (unsigned)tid;

  // --- bitonic sort (ascending). j<64 phases in-wave via shfl_xor. ---
  for (int kk = 2; kk <= SEQ; kk <<= 1) {
    for (int j = kk >> 1; j > 0; j >>= 1) {
      unsigned long long pk;
      if (j >= 64) {
        s_key[tid] = key;
        __syncthreads();
        pk = s_key[tid ^ j];
        __syncthreads();
      } else {
        pk = (unsigned long long)__shfl_xor((long long)key, j);
      }
      const bool lower = (tid & j) == 0;
      const bool dir_asc = (tid & kk) == 0;
      const bool keep_min = (dir_asc == lower);
      const bool pk_smaller = pk < key;
      key = (keep_min == pk_smaller) ? pk : key;   // distinct keys -> exact
    }
  }

  // --- sorted position == rank; scatter keep flags; emit ---
  s_keep[(int)(key & 1023ull)] = (tid < k) ? (unsigned char)1 : (unsigned char)0;
  __syncthreads();

  float o;
  if (tid == 0 || tid == sep) o = 1.0f;          // forced keep
  else o = s_keep[tid] ? 1.0f : 0.0f;            // invalid cols never top-k
  out[b * SEQ + tid] = o;
}

extern "C" void kernel_launch(void* const* d_in, const int* in_sizes, int n_in,
                              void* d_out, int out_size, void* d_ws, size_t ws_size,
                              hipStream_t stream) {
  const float* probes = (const float*)d_in[0];   // (BS, NH, SEQ, SEQ) f32
  const float* mask = (const float*)d_in[1];     // (BS, 1, 1, SEQ)  f32
  float* out = (float*)d_out;                    // (BS, SEQ)        f32

  // ws layout: [ f32 partials (BS*nch*SEQ) | f32 scores (BS*SEQ) ]
  static const int cand[] = {128, 96, 64, 48, 32, 24, 16, 12, 8, 6, 4, 3, 2, 1};
  int nch = 1;
  for (int i = 0; i < 14; ++i) {
    size_t need = (size_t)BS * cand[i] * SEQ * sizeof(float)
                + (size_t)BS * SEQ * sizeof(float);
    if (need <= ws_size) { nch = cand[i]; break; }
  }
  const int rpc = ROWS / nch;

  float* partials = (float*)d_ws;
  float* d_scores = (float*)((char*)d_ws + (size_t)BS * nch * SEQ * sizeof(float));

  dim3 grid1(nch, BS);
  colsum_partial_kernel<<<grid1, 256, 0, stream>>>(probes, partials, rpc, nch);

  dim3 grid2(BS, SEQ / 64);
  combine_kernel<<<grid2, 64, 0, stream>>>(partials, d_scores, nch);

  rank_kernel<<<BS, SEQ, 0, stream>>>(d_scores, mask, out);
}

// Round 8
// 145.489 us; speedup vs baseline: 1.0362x; 1.0362x over previous
//
#include <hip/hip_runtime.h>
#include <hip/hip_bf16.h>
#include <math.h>
#include <stdint.h>

#define BS 16
#define NH 12
#define SEQ 1024
#define ROWS (NH * SEQ)          // 12288 rows per batch
#define KEEP_FRAC 0.4f           // 1 - PRUNING_RATIO

typedef float f32x4 __attribute__((ext_vector_type(4)));

// ---------------------------------------------------------------------------
// Kernel 1: partial column-sum of probes over (h, s) rows.  [best config: R6]
// grid = (nch, BS); block = 256; thread t owns cols [4t, 4t+3] (16B loads).
// nch=128 -> 2048 blocks = exactly 8 blocks/CU -> 32/32 waves occupancy.
// NT loads: A/B-proven +18 us (R5). Per-row f64 accumulate: A/B-proven vs
// 8-row f32 tree (R7, +4.7 us) — the f64 chain hides under memory latency.
// Effective 5.8 TB/s pure read; empirical ceiling for this access pattern.
// ---------------------------------------------------------------------------
__global__ __launch_bounds__(256, 8) void colsum_partial_kernel(
    const float* __restrict__ probes, float* __restrict__ partials,
    int rows_per_chunk, int nch) {
  const int chunk = blockIdx.x;
  const int b = blockIdx.y;
  const int t = threadIdx.x;

  const size_t row0 = (size_t)b * ROWS + (size_t)chunk * rows_per_chunk;
  const f32x4* src = (const f32x4*)(probes + row0 * SEQ) + t;

  double a0 = 0.0, a1 = 0.0, a2 = 0.0, a3 = 0.0;
#pragma unroll 8
  for (int r = 0; r < rows_per_chunk; ++r) {
    f32x4 v = __builtin_nontemporal_load(src + (size_t)r * (SEQ / 4));
    a0 += v.x; a1 += v.y; a2 += v.z; a3 += v.w;
  }

  f32x4 o; o.x = (float)a0; o.y = (float)a1; o.z = (float)a2; o.w = (float)a3;
  *(f32x4*)(partials + ((size_t)b * nch + chunk) * SEQ + (size_t)t * 4) = o;
}

// ---------------------------------------------------------------------------
// Kernel 2: WIDE combine of f32 partials -> f32 scores (mean).
// grid = (BS, SEQ/64) = 256 blocks x 64 threads; partials are L3-resident.
// ---------------------------------------------------------------------------
__global__ __launch_bounds__(64) void combine_kernel(
    const float* __restrict__ partials, float* __restrict__ scores, int nch) {
  const int b = blockIdx.x;
  const int col = blockIdx.y * 64 + threadIdx.x;
  const float* p = partials + (size_t)b * nch * SEQ + col;
  double acc = 0.0;
#pragma unroll 8
  for (int c = 0; c < nch; ++c) acc += (double)p[(size_t)c * SEQ];
  scores[b * SEQ + col] = (float)(acc * (1.0 / (double)ROWS));
}

// ---------------------------------------------------------------------------
// Kernel 3: per-batch rank + mask emit. One 1024-thread block per batch.
// Packed u64 keys; bitonic sort with shfl_xor for j<64 (no LDS/barrier),
// LDS only for the 10 phases with j>=64. Reads only 4 KB of scores/block.
// ---------------------------------------------------------------------------
__global__ __launch_bounds__(1024) void rank_kernel(
    const float* __restrict__ scores, const float* __restrict__ mask,
    float* __restrict__ out) {
  const int b = blockIdx.x;
  const int tid = threadIdx.x;        // == column index
  const int lane = tid & 63;
  const int wave = tid >> 6;

  __shared__ unsigned long long s_key[SEQ];
  __shared__ int s_wred[16];
  __shared__ unsigned char s_keep[SEQ];
  __shared__ int s_len;

  // --- length = sum(mask[b,:]) via wave shuffle reduce (mask is exact 0/1) ---
  int mv = (mask[b * SEQ + tid] != 0.0f) ? 1 : 0;
#pragma unroll
  for (int o = 32; o > 0; o >>= 1) mv += __shfl_xor(mv, o);
  if (lane == 0) s_wred[wave] = mv;
  __syncthreads();
  if (tid == 0) {
    int L = 0;
#pragma unroll
    for (int w = 0; w < 16; ++w) L += s_wred[w];
    s_len = L;
  }
  __syncthreads();
  const int len = s_len;
  const int sep = len - 1;                       // len >= 128 -> sep >= 127
  const int k = (int)((float)len * KEEP_FRAC);   // bit-matches f32 ref math

  // --- build distinct sort key: ascending key == (score desc, idx asc) ---
  const float score = scores[b * SEQ + tid];
  uint32_t u = __float_as_uint(score); // scores positive -> bits monotonic
  if (tid == 0 || tid == sep) u = 0u;  // invalid -> sorts last
  unsigned long long key =
      ((unsigned long long)(u ^ 0xFFFFFFFFu) << 10) | (unsigned)tid;

  // --- bitonic sort (ascending). j<64 phases in-wave via shfl_xor. ---
  for (int kk = 2; kk <= SEQ; kk <<= 1) {
    for (int j = kk >> 1; j > 0; j >>= 1) {
      unsigned long long pk;
      if (j >= 64) {
        s_key[tid] = key;
        __syncthreads();
        pk = s_key[tid ^ j];
        __syncthreads();
      } else {
        pk = (unsigned long long)__shfl_xor((long long)key, j);
      }
      const bool lower = (tid & j) == 0;
      const bool dir_asc = (tid & kk) == 0;
      const bool keep_min = (dir_asc == lower);
      const bool pk_smaller = pk < key;
      key = (keep_min == pk_smaller) ? pk : key;   // distinct keys -> exact
    }
  }

  // --- sorted position == rank; scatter keep flags; emit ---
  s_keep[(int)(key & 1023ull)] = (tid < k) ? (unsigned char)1 : (unsigned char)0;
  __syncthreads();

  float o;
  if (tid == 0 || tid == sep) o = 1.0f;          // forced keep
  else o = s_keep[tid] ? 1.0f : 0.0f;            // invalid cols never top-k
  out[b * SEQ + tid] = o;
}

extern "C" void kernel_launch(void* const* d_in, const int* in_sizes, int n_in,
                              void* d_out, int out_size, void* d_ws, size_t ws_size,
                              hipStream_t stream) {
  const float* probes = (const float*)d_in[0];   // (BS, NH, SEQ, SEQ) f32
  const float* mask = (const float*)d_in[1];     // (BS, 1, 1, SEQ)  f32
  float* out = (float*)d_out;                    // (BS, SEQ)        f32

  // ws layout: [ f32 partials (BS*nch*SEQ) | f32 scores (BS*SEQ) ]
  static const int cand[] = {128, 96, 64, 48, 32, 24, 16, 12, 8, 6, 4, 3, 2, 1};
  int nch = 1;
  for (int i = 0; i < 14; ++i) {
    size_t need = (size_t)BS * cand[i] * SEQ * sizeof(float)
                + (size_t)BS * SEQ * sizeof(float);
    if (need <= ws_size) { nch = cand[i]; break; }
  }
  const int rpc = ROWS / nch;

  float* partials = (float*)d_ws;
  float* d_scores = (float*)((char*)d_ws + (size_t)BS * nch * SEQ * sizeof(float));

  dim3 grid1(nch, BS);
  colsum_partial_kernel<<<grid1, 256, 0, stream>>>(probes, partials, rpc, nch);

  dim3 grid2(BS, SEQ / 64);
  combine_kernel<<<grid2, 64, 0, stream>>>(partials, d_scores, nch);

  rank_kernel<<<BS, SEQ, 0, stream>>>(d_scores, mask, out);
}